// Round 12
// baseline (1248.092 us; speedup 1.0000x reference)
//
#include <hip/hip_runtime.h>
#include <stdint.h>

#define DEV __device__ __forceinline__

typedef short bf16x8 __attribute__((ext_vector_type(8)));
typedef float f32x4 __attribute__((ext_vector_type(4)));

// ---------- bf16 helpers (manual, RNE) ----------
DEV ushort f2bf(float x) {
  uint32_t u = __builtin_bit_cast(uint32_t, x);
  return (ushort)((u + 0x7fffu + ((u >> 16) & 1u)) >> 16);
}
DEV float bf2f(ushort h) { return __builtin_bit_cast(float, (uint32_t)h << 16); }

// ---------- async global->LDS (16B per lane, wave-uniform LDS base) ----------
DEV void gload_lds16(const void* g, void* l) {
  __builtin_amdgcn_global_load_lds((const __attribute__((address_space(1))) uint32_t*)g,
                                   (__attribute__((address_space(3))) uint32_t*)l, 16, 0, 0);
}

// =====================================================================
// GEMM engine (R2-proven structure; g256-stagger refuted in R9: 168us/34%
// vs this one's 146us/42% on the same shape — barrier wall at 1 blk/CU).
// 128x128 tile, BK=64, 4 waves (2x2), 64x64 per wave.
// C[M,N] = A[M,K] * W[N,K]^T, row-major bf16, K fast.
// LDS swizzle (0 conflicts measured): phys in-row byte = logical ^
//   ((row&7)<<4). Plain path: linear gload_lds dest + pre-swizzled global
//   source col. LNIN path: reg-staged A with DIRECT swizzled ds_write
//   (same LDS image; fragment reads unchanged).
// LNIN: apply LayerNorm(gamma,beta from stats buffer) + lrelu to A during
//   staging (fuses the standalone LN pass of the previous layer).
// STATS: epilogue accumulates per-row (sum, sumsq) of the raw output v
//   (pre-lrelu) via in-wave shfl reduce + 2 atomicAdds per row per wave.
//   ST zeroed by hipMemsetAsync in-launch -> rocprof replays deterministic.
// EPI: 0 f32; 1 bf16 raw; 2 bf16+lrelu; 3 f32 split (mu/lv concat weight)
// =====================================================================
template <int EPI, int LNIN, int STATS>
__global__ __launch_bounds__(256, 2) void gemm_bt(
    const ushort* __restrict__ A, int lda, const ushort* __restrict__ W, int ldb,
    void* __restrict__ Cv, long ldc, const float* __restrict__ bias,
    const float* __restrict__ bias2, long splitStride,
    const float2* __restrict__ stIn, const float* __restrict__ gam,
    const float* __restrict__ bet, float invN, float* __restrict__ stOut, int K) {
  __shared__ ushort As[128 * 64];
  __shared__ ushort Bs[128 * 64];
  const int t = threadIdx.x;
  const int l = t & 63;
  const int w = t >> 6;
  const int wr = w >> 1, wc = w & 1;
  const int rowBase = blockIdx.y << 7;
  const int colBase = blockIdx.x << 7;

  // staging lane geometry: chunk = 8 rows x 64 cols (1 KB).
  const int cr = l >> 3;                  // row within chunk (== r&7)
  const int ccol = ((l & 7) ^ cr) << 3;   // pre-swizzled col (gload_lds path)
  const int lcol = (l & 7) << 3;          // linear col (reg-staged path)
  const ushort* aS = A + (size_t)(rowBase + cr) * lda + ccol;
  const ushort* bS = W + (size_t)(colBase + cr) * ldb + ccol;
  // ds_write byte offset within chunk for reg-staged path (direct swizzle)
  const int wofs = cr * 128 + (((l & 7) << 4) ^ (cr << 4));

  f32x4 acc[4][4] = {};

  const int nk = K >> 6;
  for (int kt = 0; kt < nk; ++kt) {
    if (kt) __syncthreads();
    const int k0 = kt << 6;
    // ---- B staging: always async gload_lds (pre-swizzled source) ----
#pragma unroll
    for (int c4 = 0; c4 < 4; ++c4) {
      const int ch = (w << 2) + c4;
      gload_lds16(bS + (size_t)(ch << 3) * ldb + k0, (char*)Bs + (ch << 10));
    }
    // ---- A staging ----
    if constexpr (LNIN) {
      // reg-staged: load raw bf16 + per-row stats, normalize+lrelu, swizzled ds_write
      const float4 g0 = *(const float4*)(gam + k0 + lcol);
      const float4 g1 = *(const float4*)(gam + k0 + lcol + 4);
      const float4 be0 = *(const float4*)(bet + k0 + lcol);
      const float4 be1 = *(const float4*)(bet + k0 + lcol + 4);
      bf16x8 raw[4];
      float2 st[4];
#pragma unroll
      for (int c4 = 0; c4 < 4; ++c4) {
        const int ch = (w << 2) + c4;
        const int ar = rowBase + (ch << 3) + cr;
        raw[c4] = *(const bf16x8*)(A + (size_t)ar * lda + k0 + lcol);
        st[c4] = stIn[ar];
      }
      const float gv[8] = {g0.x, g0.y, g0.z, g0.w, g1.x, g1.y, g1.z, g1.w};
      const float bv[8] = {be0.x, be0.y, be0.z, be0.w, be1.x, be1.y, be1.z, be1.w};
#pragma unroll
      for (int c4 = 0; c4 < 4; ++c4) {
        const int ch = (w << 2) + c4;
        const float mean = st[c4].x * invN;
        const float rstd = rsqrtf(st[c4].y * invN - mean * mean + 1e-5f);
        bf16x8 o;
#pragma unroll
        for (int j = 0; j < 8; ++j) {
          float v = (bf2f((ushort)raw[c4][j]) - mean) * rstd * gv[j] + bv[j];
          v = v >= 0.f ? v : 0.2f * v;
          o[j] = (short)f2bf(v);
        }
        *(bf16x8*)((char*)As + (ch << 10) + wofs) = o;
      }
    } else {
#pragma unroll
      for (int c4 = 0; c4 < 4; ++c4) {
        const int ch = (w << 2) + c4;
        gload_lds16(aS + (size_t)(ch << 3) * lda + k0, (char*)As + (ch << 10));
      }
    }
    __syncthreads();  // drains vmcnt+lgkmcnt before barrier -> tile visible

    bf16x8 af[2][4], bw[2][4];
    const int koff = (l >> 4) << 4;
#pragma unroll
    for (int mi = 0; mi < 4; ++mi) {
      const int r = (wr << 6) + (mi << 4) + (l & 15);
      const char* rp = (const char*)As + (r << 7);
      const int sw = (r & 7) << 4;
      af[0][mi] = *(const bf16x8*)(rp + (koff ^ sw));
      af[1][mi] = *(const bf16x8*)(rp + ((64 + koff) ^ sw));
    }
#pragma unroll
    for (int ni = 0; ni < 4; ++ni) {
      const int r = (wc << 6) + (ni << 4) + (l & 15);
      const char* rp = (const char*)Bs + (r << 7);
      const int sw = (r & 7) << 4;
      bw[0][ni] = *(const bf16x8*)(rp + (koff ^ sw));
      bw[1][ni] = *(const bf16x8*)(rp + ((64 + koff) ^ sw));
    }
#pragma unroll
    for (int kk = 0; kk < 2; ++kk)
#pragma unroll
      for (int mi = 0; mi < 4; ++mi)
#pragma unroll
        for (int ni = 0; ni < 4; ++ni)
          acc[mi][ni] = __builtin_amdgcn_mfma_f32_16x16x32_bf16(
              af[kk][mi], bw[kk][ni], acc[mi][ni], 0, 0, 0);
  }

  // ---- epilogue: C/D layout col = l&15, row = (l>>4)*4 + j ----
  const int orow = (l >> 4) << 2;
  const int ocol = l & 15;
  float ps[4][4] = {};
  float pq[4][4] = {};
#pragma unroll
  for (int ni = 0; ni < 4; ++ni) {
    const int col = colBase + (wc << 6) + (ni << 4) + ocol;
    float bv;
    if constexpr (EPI == 3)
      bv = (col < 256) ? bias[col] : bias2[col - 256];
    else
      bv = bias[col];
#pragma unroll
    for (int mi = 0; mi < 4; ++mi) {
      const int row0 = rowBase + (wr << 6) + (mi << 4) + orow;
#pragma unroll
      for (int j = 0; j < 4; ++j) {
        float v = acc[mi][ni][j] + bv;
        if constexpr (STATS) {
          ps[mi][j] += v;  // stats on RAW value (LN comes before lrelu)
          pq[mi][j] += v * v;
        }
        if constexpr (EPI == 2) v = v >= 0.f ? v : 0.2f * v;
        if constexpr (EPI == 0) {
          ((float*)Cv)[(long)(row0 + j) * ldc + col] = v;
        } else if constexpr (EPI == 3) {
          const long idx =
              (long)(row0 + j) * 256 + (col & 255) + (long)(col >> 8) * splitStride;
          ((float*)Cv)[idx] = v;
        } else {
          ((ushort*)Cv)[(long)(row0 + j) * ldc + col] = f2bf(v);
        }
      }
    }
  }
  if constexpr (STATS) {
    // reduce over the 16 lanes sharing (l>>4): they cover this wave's 64 cols
#pragma unroll
    for (int mi = 0; mi < 4; ++mi)
#pragma unroll
      for (int j = 0; j < 4; ++j) {
        float s = ps[mi][j], q = pq[mi][j];
#pragma unroll
        for (int d = 1; d < 16; d <<= 1) {
          s += __shfl_xor(s, d);
          q += __shfl_xor(q, d);
        }
        if ((l & 15) == 0) {
          const int r = rowBase + (wr << 6) + (mi << 4) + orow + j;
          atomicAdd(stOut + 2 * r, s);
          atomicAdd(stOut + 2 * r + 1, q);
        }
      }
  }
}

// =====================================================================
// z = mu + eps*exp(0.5*lv); attn = softmax(z @ ctx^T); z_enh = z + 0.1*attn@ctx
// =====================================================================
__global__ __launch_bounds__(256) void reparam_attn(
    const float* __restrict__ mu, const float* __restrict__ lv,
    const float* __restrict__ eps, const float* __restrict__ ctx,
    ushort* __restrict__ zb) {
  __shared__ float ctx_lds[32][257];
  __shared__ float z_lds[4][256];
  __shared__ float w_lds[4][32];
  const int t = threadIdx.x;
  for (int i = t; i < 32 * 256; i += 256) ctx_lds[i >> 8][i & 255] = ctx[i];
  __syncthreads();
  const int l = t & 63, wv = t >> 6;
  const int gw = blockIdx.x * 4 + wv;
  const int m = l & 31, half = l >> 5;
  for (int it = 0; it < 8; ++it) {
    const int r = gw + 4096 * it;
    const size_t base = (size_t)r * 256;
    float z[4];
#pragma unroll
    for (int j = 0; j < 4; ++j) {
      const int c = l + 64 * j;
      z[j] = mu[base + c] + eps[base + c] * __expf(0.5f * lv[base + c]);
      z_lds[wv][c] = z[j];
    }
    __syncthreads();
    float s = 0.f;
#pragma unroll 4
    for (int i2 = 0; i2 < 128; ++i2) {
      const int c = half * 128 + i2;
      s += ctx_lds[m][c] * z_lds[wv][c];
    }
    s += __shfl_xor(s, 32);
    float mx = s;
#pragma unroll
    for (int d2 = 16; d2; d2 >>= 1) mx = fmaxf(mx, __shfl_xor(mx, d2));
    const float e = __expf(s - mx);
    float sm = e;
#pragma unroll
    for (int d2 = 16; d2; d2 >>= 1) sm += __shfl_xor(sm, d2);
    w_lds[wv][m] = e / sm;
    __syncthreads();
#pragma unroll
    for (int j = 0; j < 4; ++j) {
      const int c = l + 64 * j;
      float a = 0.f;
#pragma unroll 8
      for (int mm = 0; mm < 32; ++mm) a += w_lds[wv][mm] * ctx_lds[mm][c];
      zb[base + c] = f2bf(z[j] + 0.1f * a);
    }
    __syncthreads();
  }
}

// ---------- f32 -> bf16 conversion for x + 8 weight tensors ----------
struct ConvArgs {
  const float* src[9];
  ushort* dst[9];
  int n4[9];
};
__global__ __launch_bounds__(256) void conv_bf16(ConvArgs a) {
  const int y = blockIdx.y;
  const float4* s = (const float4*)a.src[y];
  ushort4* d = (ushort4*)a.dst[y];
  const int n4 = a.n4[y];
  const int stride = gridDim.x * 256;
  for (int i = blockIdx.x * 256 + threadIdx.x; i < n4; i += stride) {
    float4 v = s[i];
    ushort4 o;
    o.x = f2bf(v.x); o.y = f2bf(v.y); o.z = f2bf(v.z); o.w = f2bf(v.w);
    d[i] = o;
  }
}

// =====================================================================
// Host side
// =====================================================================
extern "C" void kernel_launch(void* const* d_in, const int* in_sizes, int n_in,
                              void* d_out, int out_size, void* d_ws, size_t ws_size,
                              hipStream_t stream) {
  constexpr size_t NB = 32768, ND = 768, NL = 256;

  const float* x = (const float*)d_in[0];
  const float* eps = (const float*)d_in[1];

  char* ws = (char*)d_ws;
  // Workspace (217 MB):
  //  [0, 67.1M)       XB (dead after enc1) / T1
  //  [67.1M, 134.2M)  T2; T3 spans [67.1M, 201.3M) (T2 dead at dec2)
  //  [134.2M, 201.3M) ZB (consumed by di before dec2's T3 overwrites)
  //  [201.3M, 216.0M) weights (wmu+wlv adjacent -> [512,1024])
  //  [216.0M, 217.1M) LN stats: 4 x 32768 x float2
  ushort* XB = (ushort*)(ws + 0);
  ushort* T1 = (ushort*)(ws + 0);
  ushort* T2 = (ushort*)(ws + 67108864ull);
  ushort* T3 = (ushort*)(ws + 67108864ull);
  ushort* ZB = (ushort*)(ws + 134217728ull);
  ushort* WB = (ushort*)(ws + 201326592ull);
  float2* ST = (float2*)(ws + 216006656ull);
  float2* st1 = ST;
  float2* st2 = st1 + 32768;
  float2* st3 = st2 + 32768;
  float2* st4 = st3 + 32768;

  ushort* w1 = WB;               // [1024,768]
  ushort* w2 = w1 + 786432;      // [1024,1024]
  ushort* wmu = w2 + 1048576;    // [256,1024]  (wlv adjacent -> [512,1024])
  ushort* wlv = wmu + 262144;    // [256,1024]
  ushort* wdi = wlv + 262144;    // [1024,256]
  ushort* wd1 = wdi + 262144;    // [1024,1024]
  ushort* wd2 = wd1 + 1048576;   // [2048,1024]
  ushort* wd3 = wd2 + 2097152;   // [768,2048]

  hipMemsetAsync(ST, 0, 4 * 32768 * sizeof(float2), stream);

  ConvArgs ca;
  ca.src[0] = x;                      ca.dst[0] = XB;  ca.n4[0] = (int)(NB * ND / 4);
  ca.src[1] = (const float*)d_in[2];  ca.dst[1] = w1;  ca.n4[1] = 786432 / 4;
  ca.src[2] = (const float*)d_in[6];  ca.dst[2] = w2;  ca.n4[2] = 1048576 / 4;
  ca.src[3] = (const float*)d_in[10]; ca.dst[3] = wmu; ca.n4[3] = 262144 / 4;
  ca.src[4] = (const float*)d_in[12]; ca.dst[4] = wlv; ca.n4[4] = 262144 / 4;
  ca.src[5] = (const float*)d_in[14]; ca.dst[5] = wdi; ca.n4[5] = 262144 / 4;
  ca.src[6] = (const float*)d_in[16]; ca.dst[6] = wd1; ca.n4[6] = 1048576 / 4;
  ca.src[7] = (const float*)d_in[20]; ca.dst[7] = wd2; ca.n4[7] = 2097152 / 4;
  ca.src[8] = (const float*)d_in[24]; ca.dst[8] = wd3; ca.n4[8] = 1572864 / 4;
  conv_bf16<<<dim3(1024, 9), 256, 0, stream>>>(ca);

  float* out = (float*)d_out;
  float* mu_o = out + NB * ND;
  float* lv_o = mu_o + NB * NL;
  const long SPLIT = (long)NB * 256;
  const float i1024 = 1.0f / 1024.f, i2048 = 1.0f / 2048.f;

  // enc1: raw h1 -> T2, stats1
  gemm_bt<1, 0, 1><<<dim3(8, 256), 256, 0, stream>>>(
      XB, 768, w1, 768, T2, 1024, (const float*)d_in[3], nullptr, 0,
      nullptr, nullptr, nullptr, 0.f, (float*)st1, 768);
  // enc2: A = LN1(T2)+lrelu (fused), raw h2 -> T1, stats2
  gemm_bt<1, 1, 1><<<dim3(8, 256), 256, 0, stream>>>(
      T2, 1024, w2, 1024, T1, 1024, (const float*)d_in[7], nullptr, 0,
      st1, (const float*)d_in[4], (const float*)d_in[5], i1024, (float*)st2, 1024);
  // mu & lv in one GEMM: A = LN2(T1)+lrelu (fused), split f32 outputs
  gemm_bt<3, 1, 0><<<dim3(4, 256), 256, 0, stream>>>(
      T1, 1024, wmu, 1024, mu_o, 256, (const float*)d_in[11], (const float*)d_in[13],
      SPLIT, st2, (const float*)d_in[8], (const float*)d_in[9], i1024, nullptr, 1024);
  // reparameterize + context attention -> z_enh (bf16)
  reparam_attn<<<1024, 256, 0, stream>>>(mu_o, lv_o, eps, (const float*)d_in[26], ZB);
  // di: plain A, bias+lrelu -> T2
  gemm_bt<2, 0, 0><<<dim3(8, 256), 256, 0, stream>>>(
      ZB, 256, wdi, 256, T2, 1024, (const float*)d_in[15], nullptr, 0,
      nullptr, nullptr, nullptr, 0.f, nullptr, 256);
  // dec1: raw -> T1, stats3
  gemm_bt<1, 0, 1><<<dim3(8, 256), 256, 0, stream>>>(
      T2, 1024, wd1, 1024, T1, 1024, (const float*)d_in[17], nullptr, 0,
      nullptr, nullptr, nullptr, 0.f, (float*)st3, 1024);
  // dec2: A = LN3(T1)+lrelu (fused), raw -> T3, stats4
  gemm_bt<1, 1, 1><<<dim3(16, 256), 256, 0, stream>>>(
      T1, 1024, wd2, 1024, T3, 2048, (const float*)d_in[21], nullptr, 0,
      st3, (const float*)d_in[18], (const float*)d_in[19], i1024, (float*)st4, 1024);
  // dec3: A = LN4(T3)+lrelu (fused), f32 out
  gemm_bt<0, 1, 0><<<dim3(6, 256), 256, 0, stream>>>(
      T3, 2048, wd3, 2048, out, 768, (const float*)d_in[25], nullptr, 0,
      st4, (const float*)d_in[22], (const float*)d_in[23], i2048, nullptr, 2048);
}